// Round 7
// baseline (332.249 us; speedup 1.0000x reference)
//
#include <hip/hip_runtime.h>
#include <math.h>

#define BB 1024
#define LSx 128
#define LLx 2048
#define TOPKx 48

// ---------------------------------------------------------------------------
// Kernel 1: long-term LSH scoring (VERBATIM from R6 verified 80us version).
// ---------------------------------------------------------------------------
__global__ __launch_bounds__(256, 2) void k_score(
    const int* __restrict__ lg, const int* __restrict__ lsh, const int* __restrict__ lc,
    const int* __restrict__ ig, const int* __restrict__ ish, const int* __restrict__ ici,
    const float* __restrict__ emb, const float* __restrict__ Hm,
    signed char* __restrict__ gsc)
{
  __shared__ float Xitem[48];
  __shared__ int icode[16];
  __shared__ __align__(16) float4 xsh[256][5];   // slot 4 = pad -> 20-word stride
  const int b = blockIdx.y, tid = threadIdx.x;

  const int l = blockIdx.x * 256 + tid;
  const size_t off = (size_t)b * LLx + l;
  const int gid = lg[off];

  if (tid < 48) {
    const int seg = tid >> 4, e = tid & 15;
    const int id = (seg == 0) ? ig[b] : (seg == 1) ? ish[b] : ici[b];
    Xitem[tid] = emb[(size_t)id * 16 + e];
  }
  __syncthreads();
  if (tid < 16) {
    float dd = 0.f;
    for (int e = 0; e < 48; ++e) dd += Xitem[e] * Hm[e * 16 + tid];
    icode[tid] = (dd > 0.f) ? 1 : (dd < 0.f ? -1 : 0);
  }

  const int srow = tid >> 2;
  const int q = tid & 3;
  const size_t bbase = (size_t)b * LLx + (size_t)blockIdx.x * 256;

  float d[16];
  #pragma unroll
  for (int m = 0; m < 16; ++m) d[m] = 0.f;

  #pragma unroll
  for (int seg = 0; seg < 3; ++seg) {
    const int* idarr = (seg == 0) ? lg : (seg == 1) ? lsh : lc;
    #pragma unroll
    for (int jj = 0; jj < 4; ++jj) {
      const int pos = jj * 64 + srow;
      const int id = idarr[bbase + pos];
      xsh[pos][q] = *(const float4*)(emb + (size_t)id * 16 + q * 4);
    }
    __syncthreads();
    if (gid != 0) {
      float x[16];
      #pragma unroll
      for (int qq = 0; qq < 4; ++qq) {
        const float4 r = xsh[tid][qq];
        x[qq * 4 + 0] = r.x; x[qq * 4 + 1] = r.y;
        x[qq * 4 + 2] = r.z; x[qq * 4 + 3] = r.w;
      }
      const float* hb = Hm + seg * 256;
      #pragma unroll
      for (int i = 0; i < 16; ++i) {
        const float xi = x[i];
        #pragma unroll
        for (int mc = 0; mc < 4; ++mc) {
          const float4 h4 = *(const float4*)(hb + i * 16 + mc * 4);
          d[mc * 4 + 0] += xi * h4.x;
          d[mc * 4 + 1] += xi * h4.y;
          d[mc * 4 + 2] += xi * h4.z;
          d[mc * 4 + 3] += xi * h4.w;
        }
      }
    }
    if (seg < 2) __syncthreads();
  }

  int sc = -1;
  if (gid != 0) {
    sc = 0;
    #pragma unroll
    for (int m = 0; m < 16; ++m) {
      const int cs = (d[m] > 0.f) ? 1 : (d[m] < 0.f ? -1 : 0);
      sc += (cs == icode[m]) ? 1 : 0;
    }
  }
  gsc[off] = (signed char)sc;
}

// ---------------------------------------------------------------------------
// Kernel 2: fused tail — topk + {short-MHA (waves 0-1) || long-MHA (waves
// 2-3)} + MLP. One 256-thread block per batch element. All __syncthreads at
// top level; both halves reach every barrier. Per-half valid-counts via
// per-wave ballot (replaces block-wide __syncthreads_count, same values).
// All arithmetic chains verbatim from the verified kernels -> bit-identical.
// ---------------------------------------------------------------------------
__device__ __forceinline__ float block_sum256(float v, float* red) {
  #pragma unroll
  for (int m = 32; m >= 1; m >>= 1) v += __shfl_xor(v, m, 64);
  const int lane = threadIdx.x & 63, wave = threadIdx.x >> 6;
  if (lane == 0) red[wave] = v;
  __syncthreads();
  const float t = red[0] + red[1] + red[2] + red[3];
  __syncthreads();
  return t;
}

__global__ __launch_bounds__(256) void k_fused(
    const int* __restrict__ sg, const int* __restrict__ ss, const int* __restrict__ scd,
    const int* __restrict__ lg, const int* __restrict__ ls, const int* __restrict__ lcd,
    const int* __restrict__ ig, const int* __restrict__ ish, const int* __restrict__ ici,
    const int* __restrict__ uid, const int* __restrict__ u1, const int* __restrict__ u2,
    const int* __restrict__ u3, const int* __restrict__ u4,
    const float* __restrict__ emb,
    const float* __restrict__ sWq, const float* __restrict__ sbq,
    const float* __restrict__ sWk, const float* __restrict__ sbk,
    const float* __restrict__ sWv, const float* __restrict__ sbv,
    const float* __restrict__ sWo, const float* __restrict__ sbo,
    const float* __restrict__ lWq, const float* __restrict__ lbq,
    const float* __restrict__ lWk, const float* __restrict__ lbk,
    const float* __restrict__ lWv, const float* __restrict__ lbv,
    const float* __restrict__ lWo, const float* __restrict__ lbo,
    const signed char* __restrict__ gsc,
    const float* __restrict__ W1, const float* __restrict__ b1,
    const float* __restrict__ g1, const float* __restrict__ be1,
    const float* __restrict__ W2, const float* __restrict__ b2,
    const float* __restrict__ g2, const float* __restrict__ be2,
    const float* __restrict__ W3, const float* __restrict__ b3,
    float* __restrict__ out)
{
  __shared__ float Xitem[48];
  __shared__ float qh_s[48], qh_l[48];
  __shared__ __align__(16) float vhs_s[LSx][48];
  __shared__ float scs_s[8][LSx + 4];
  __shared__ __align__(16) float vhs_l[TOPKx][48];
  __shared__ float scs_l[8][TOPKx + 4];
  __shared__ float osm_s[48], osm_l[48];
  __shared__ unsigned char validf_s[LSx];
  __shared__ unsigned char validf_l[TOPKx];
  __shared__ int hist[18], wsum[4], nv[4], selsh[TOPKx];
  __shared__ int cnt_above;
  __shared__ __align__(16) float x[224];
  __shared__ __align__(16) float h1[200];
  __shared__ float h2[80];
  __shared__ float red[4];

  const int b = blockIdx.x, tid = threadIdx.x;
  const bool shorth = tid < 128;
  const int t = shorth ? tid : tid - 128;

  // each thread owns 8 contiguous scores, in registers (verbatim k_topk)
  const int2 myv = ((const int2*)(gsc + (size_t)b * LLx))[tid];
  signed char loc[8];
  *(int2*)loc = myv;

  // ---- P0: item embed + user embed + topk init ----
  if (tid < 48) {
    const int seg = tid >> 4, e = tid & 15;
    const int id = (seg == 0) ? ig[b] : (seg == 1) ? ish[b] : ici[b];
    Xitem[tid] = emb[(size_t)id * 16 + e];
  }
  if (tid >= 160 && tid < 240) {
    const int u = tid - 160;
    const int f = u >> 4;
    const int id = (f == 0) ? uid[b] : (f == 1) ? u1[b] : (f == 2) ? u2[b]
                 : (f == 3) ? u3[b] : u4[b];
    x[48 + u] = emb[(size_t)id * 16 + (u & 15)];   // (48+u)&15 == u&15
  }
  if (tid < 18) hist[tid] = 0;
  if (tid == 0) cnt_above = 0;
  __syncthreads();

  // ---- P1: histogram atomics + both q projections + x[0:48] copy ----
  #pragma unroll
  for (int j = 0; j < 8; ++j) atomicAdd(&hist[(int)loc[j] + 1], 1);
  if (tid < 48) {
    float a = sbq[tid];
    for (int e = 0; e < 48; ++e) a += Xitem[e] * sWq[e * 48 + tid];
    qh_s[tid] = a;
  } else if (tid >= 64 && tid < 112) {
    x[tid - 64] = Xitem[tid - 64];
  } else if (tid >= 128 && tid < 176) {
    float a = lbq[t];
    for (int e = 0; e < 48; ++e) a += Xitem[e] * lWq[e * 48 + t];
    qh_l[t] = a;
  }
  __syncthreads();

  // ---- P2: threshold + tie-rank scan (verbatim k_topk) ----
  int above = 0, tval = -1, need = 0;
  for (int s = 16; s >= -1; --s) {
    const int c = hist[s + 1];
    if (above + c >= TOPKx) { tval = s; need = TOPKx - above; break; }
    above += c;
  }
  const int base_l = tid * (LLx / 256);
  int cnt = 0;
  #pragma unroll
  for (int j = 0; j < 8; ++j) cnt += ((int)loc[j] == tval) ? 1 : 0;
  int v = cnt;
  const int lane = tid & 63, wave = tid >> 6;
  #pragma unroll
  for (int o = 1; o < 64; o <<= 1) {
    const int u = __shfl_up(v, o, 64);
    if (lane >= o) v += u;
  }
  if (lane == 63) wsum[wave] = v;
  __syncthreads();
  int rank = v - cnt;
  for (int w = 0; w < wave; ++w) rank += wsum[w];

  #pragma unroll
  for (int j = 0; j < 8; ++j) {
    const int l = base_l + j;
    const int s = (int)loc[j];
    if (s > tval) {
      const int slot = atomicAdd(&cnt_above, 1);
      selsh[slot] = l;
    } else if (s == tval) {
      if (rank < need) selsh[above + rank] = l;
      ++rank;
    }
  }
  __syncthreads();   // selsh ready

  // ---- P4: key id loads + per-half valid counts ----
  int gid = 0, sid = 0, cid = 0;
  if (shorth) {
    const size_t off = (size_t)b * LSx + t;
    gid = sg[off]; sid = ss[off]; cid = scd[off];
  } else if (t < TOPKx) {
    const int pos = selsh[t];
    const size_t off = (size_t)b * LLx + pos;
    gid = lg[off]; sid = ls[off]; cid = lcd[off];
  }
  const unsigned long long bal = __ballot(gid != 0);
  if ((tid & 63) == 0) nv[tid >> 6] = __popcll(bal);
  __syncthreads();
  const int nval = shorth ? (nv[0] + nv[1]) : (nv[2] + nv[3]);

  // ---- P5: K/V projections (verbatim chains, disjoint halves) ----
  if (shorth) {
    validf_s[t] = (unsigned char)(t < nval);   // short: mask = position < slen
    float kh[48], vh[48];
    #pragma unroll
    for (int j = 0; j < 48; ++j) { kh[j] = sbk[j]; vh[j] = sbv[j]; }
    const int ids3[3] = {gid, sid, cid};
    #pragma unroll
    for (int seg = 0; seg < 3; ++seg) {
      const float* row = emb + (size_t)ids3[seg] * 16;
      #pragma unroll
      for (int i4 = 0; i4 < 4; ++i4) {
        const float4 xv = ((const float4*)row)[i4];
        const float xs[4] = {xv.x, xv.y, xv.z, xv.w};
        #pragma unroll
        for (int c = 0; c < 4; ++c) {
          const int e = seg * 16 + i4 * 4 + c;
          const float* wkr = sWk + e * 48;
          const float* wvr = sWv + e * 48;
          const float xe = xs[c];
          #pragma unroll
          for (int j = 0; j < 48; ++j) {
            kh[j] += xe * wkr[j];
            vh[j] += xe * wvr[j];
          }
        }
      }
    }
    #pragma unroll
    for (int h = 0; h < 8; ++h) {
      float s = 0.f;
      #pragma unroll
      for (int d = 0; d < 6; ++d) s += qh_s[h * 6 + d] * kh[h * 6 + d];
      scs_s[h][t] = s * 0.40824829046386301637f;   // 1/sqrt(6)
    }
    #pragma unroll
    for (int j = 0; j < 48; ++j) vhs_s[t][j] = vh[j];
  } else if (t < TOPKx) {
    validf_l[t] = (unsigned char)(gid != 0);   // long: mask = gid != 0
    float kh[48], vh[48];
    #pragma unroll
    for (int j = 0; j < 48; ++j) { kh[j] = lbk[j]; vh[j] = lbv[j]; }
    const int ids3[3] = {gid, sid, cid};
    #pragma unroll
    for (int seg = 0; seg < 3; ++seg) {
      const float* row = emb + (size_t)ids3[seg] * 16;
      #pragma unroll
      for (int i4 = 0; i4 < 4; ++i4) {
        const float4 xv = ((const float4*)row)[i4];
        const float xs[4] = {xv.x, xv.y, xv.z, xv.w};
        #pragma unroll
        for (int c = 0; c < 4; ++c) {
          const int e = seg * 16 + i4 * 4 + c;
          const float* wkr = lWk + e * 48;
          const float* wvr = lWv + e * 48;
          const float xe = xs[c];
          #pragma unroll
          for (int j = 0; j < 48; ++j) {
            kh[j] += xe * wkr[j];
            vh[j] += xe * wvr[j];
          }
        }
      }
    }
    #pragma unroll
    for (int h = 0; h < 8; ++h) {
      float s = 0.f;
      #pragma unroll
      for (int d = 0; d < 6; ++d) s += qh_l[h * 6 + d] * kh[h * 6 + d];
      scs_l[h][t] = s * 0.40824829046386301637f;
    }
    #pragma unroll
    for (int j = 0; j < 48; ++j) vhs_l[t][j] = vh[j];
  }
  __syncthreads();

  // ---- P6: softmax (each half: 8 head-groups of 16 lanes, verbatim) ----
  {
    const int h = t >> 4, l16 = t & 15;
    if (shorth) {
      float amax = -INFINITY;
      for (int k = l16; k < LSx; k += 16) if (validf_s[k]) amax = fmaxf(amax, scs_s[h][k]);
      #pragma unroll
      for (int m = 1; m < 16; m <<= 1) amax = fmaxf(amax, __shfl_xor(amax, m, 16));
      if (nval == 0) {
        for (int k = l16; k < LSx; k += 16) scs_s[h][k] = 1.0f / (float)LSx;
      } else {
        float ssum = 0.f;
        for (int k = l16; k < LSx; k += 16) {
          const float ev = validf_s[k] ? expf(scs_s[h][k] - amax) : 0.f;
          scs_s[h][k] = ev;
          ssum += ev;
        }
        #pragma unroll
        for (int m = 1; m < 16; m <<= 1) ssum += __shfl_xor(ssum, m, 16);
        const float inv = 1.0f / ssum;
        for (int k = l16; k < LSx; k += 16) scs_s[h][k] *= inv;
      }
    } else {
      float amax = -INFINITY;
      for (int k = l16; k < TOPKx; k += 16) if (validf_l[k]) amax = fmaxf(amax, scs_l[h][k]);
      #pragma unroll
      for (int m = 1; m < 16; m <<= 1) amax = fmaxf(amax, __shfl_xor(amax, m, 16));
      if (nval == 0) {
        for (int k = l16; k < TOPKx; k += 16) scs_l[h][k] = 1.0f / (float)TOPKx;
      } else {
        float ssum = 0.f;
        for (int k = l16; k < TOPKx; k += 16) {
          const float ev = validf_l[k] ? expf(scs_l[h][k] - amax) : 0.f;
          scs_l[h][k] = ev;
          ssum += ev;
        }
        #pragma unroll
        for (int m = 1; m < 16; m <<= 1) ssum += __shfl_xor(ssum, m, 16);
        const float inv = 1.0f / ssum;
        for (int k = l16; k < TOPKx; k += 16) scs_l[h][k] *= inv;
      }
    }
  }
  __syncthreads();

  // ---- P7: PV (verbatim) ----
  if (tid < 48) {
    const int h = tid / 6;
    float a = 0.f;
    for (int k = 0; k < LSx; ++k) a += scs_s[h][k] * vhs_s[k][tid];
    osm_s[tid] = a;
  } else if (!shorth && t < 48) {
    const int h = t / 6;
    float a = 0.f;
    for (int k = 0; k < TOPKx; ++k) a += scs_l[h][k] * vhs_l[k][t];
    osm_l[t] = a;
  }
  __syncthreads();

  // ---- P8: output projections into MLP input x (verbatim chains) ----
  if (tid < 48) {
    float r = sbo[tid];
    for (int j = 0; j < 48; ++j) r += osm_s[j] * sWo[j * 48 + tid];
    x[128 + tid] = r;
  } else if (!shorth && t < 48) {
    float r = lbo[t];
    for (int j = 0; j < 48; ++j) r += osm_l[j] * lWo[j * 48 + t];
    x[176 + t] = r;
  }
  __syncthreads();

  // ---- P9: MLP head (verbatim k_mlp body) ----
  float v1 = 0.f;
  if (tid < 200) {
    v1 = b1[tid];
    for (int i4 = 0; i4 < 56; ++i4) {
      const float4 xv = *(const float4*)(x + i4 * 4);
      const float* w = W1 + i4 * 4 * 200 + tid;
      v1 += xv.x * w[0];
      v1 += xv.y * w[200];
      v1 += xv.z * w[400];
      v1 += xv.w * w[600];
    }
  }
  const float mean1 = block_sum256((tid < 200) ? v1 : 0.f, red) * (1.0f / 200.0f);
  const float dv = (tid < 200) ? (v1 - mean1) : 0.f;
  const float var1 = block_sum256(dv * dv, red) * (1.0f / 200.0f);
  if (tid < 200) {
    const float y = (v1 - mean1) * rsqrtf(var1 + 1e-3f) * g1[tid] + be1[tid];
    h1[tid] = fmaxf(y, 0.f);
  }
  __syncthreads();

  float v2 = 0.f;
  if (tid < 80) {
    v2 = b2[tid];
    for (int i4 = 0; i4 < 50; ++i4) {
      const float4 xv = *(const float4*)(h1 + i4 * 4);
      const float* w = W2 + i4 * 4 * 80 + tid;
      v2 += xv.x * w[0];
      v2 += xv.y * w[80];
      v2 += xv.z * w[160];
      v2 += xv.w * w[240];
    }
  }
  const float mean2 = block_sum256((tid < 80) ? v2 : 0.f, red) * (1.0f / 80.0f);
  const float dv2 = (tid < 80) ? (v2 - mean2) : 0.f;
  const float var2 = block_sum256(dv2 * dv2, red) * (1.0f / 80.0f);
  if (tid < 80) {
    const float y = (v2 - mean2) * rsqrtf(var2 + 1e-3f) * g2[tid] + be2[tid];
    h2[tid] = fmaxf(y, 0.f);
  }
  __syncthreads();

  const float p = (tid < 80) ? h2[tid] * W3[tid] : 0.f;
  const float z = block_sum256(p, red);
  if (tid == 0) {
    out[b] = 1.0f / (1.0f + expf(-(z + b3[0])));
  }
}

// ---------------------------------------------------------------------------
extern "C" void kernel_launch(void* const* d_in, const int* in_sizes, int n_in,
                              void* d_out, int out_size, void* d_ws, size_t ws_size,
                              hipStream_t stream) {
  (void)in_sizes; (void)n_in; (void)out_size; (void)ws_size;
  const int* uid = (const int*)d_in[0];
  const int* u1  = (const int*)d_in[1];
  const int* u2  = (const int*)d_in[2];
  const int* u3  = (const int*)d_in[3];
  const int* u4  = (const int*)d_in[4];
  const int* ig  = (const int*)d_in[5];
  const int* ish = (const int*)d_in[6];
  const int* ici = (const int*)d_in[7];
  const int* sg  = (const int*)d_in[8];
  const int* ss  = (const int*)d_in[9];
  const int* scd = (const int*)d_in[10];
  const int* lg  = (const int*)d_in[11];
  const int* ls  = (const int*)d_in[12];
  const int* lcd = (const int*)d_in[13];
  const float* emb = (const float*)d_in[14];
  const float* Hm  = (const float*)d_in[15];
  const float* sWq = (const float*)d_in[16];
  const float* sbq = (const float*)d_in[17];
  const float* sWk = (const float*)d_in[18];
  const float* sbk = (const float*)d_in[19];
  const float* sWv = (const float*)d_in[20];
  const float* sbv = (const float*)d_in[21];
  const float* sWo = (const float*)d_in[22];
  const float* sbo = (const float*)d_in[23];
  const float* lWq = (const float*)d_in[24];
  const float* lbq = (const float*)d_in[25];
  const float* lWk = (const float*)d_in[26];
  const float* lbk = (const float*)d_in[27];
  const float* lWv = (const float*)d_in[28];
  const float* lbv = (const float*)d_in[29];
  const float* lWo = (const float*)d_in[30];
  const float* lbo = (const float*)d_in[31];
  const float* W1 = (const float*)d_in[32];
  const float* b1 = (const float*)d_in[33];
  const float* g1 = (const float*)d_in[34];
  const float* be1 = (const float*)d_in[35];
  const float* W2 = (const float*)d_in[36];
  const float* b2 = (const float*)d_in[37];
  const float* g2 = (const float*)d_in[38];
  const float* be2 = (const float*)d_in[39];
  const float* W3 = (const float*)d_in[40];
  const float* b3 = (const float*)d_in[41];
  float* out = (float*)d_out;

  // workspace: [gsc i8: BB*LLx = 2MB]
  signed char* gsc = (signed char*)d_ws;

  k_score<<<dim3(LLx / 256, BB), dim3(256), 0, stream>>>(
      lg, ls, lcd, ig, ish, ici, emb, Hm, gsc);
  k_fused<<<dim3(BB), dim3(256), 0, stream>>>(
      sg, ss, scd, lg, ls, lcd, ig, ish, ici,
      uid, u1, u2, u3, u4, emb,
      sWq, sbq, sWk, sbk, sWv, sbv, sWo, sbo,
      lWq, lbq, lWk, lbk, lWv, lbv, lWo, lbo,
      gsc,
      W1, b1, g1, be1, W2, b2, g2, be2, W3, b3, out);
}

// Round 8
// 328.206 us; speedup vs baseline: 1.0123x; 1.0123x over previous
//
#include <hip/hip_runtime.h>
#include <math.h>

#define BB 1024
#define LSx 128
#define LLx 2048
#define TOPKx 48

// ---------------------------------------------------------------------------
// Kernel 1: long-term LSH scoring (VERBATIM from R6 verified 80us version).
// ---------------------------------------------------------------------------
__global__ __launch_bounds__(256, 2) void k_score(
    const int* __restrict__ lg, const int* __restrict__ lsh, const int* __restrict__ lc,
    const int* __restrict__ ig, const int* __restrict__ ish, const int* __restrict__ ici,
    const float* __restrict__ emb, const float* __restrict__ Hm,
    signed char* __restrict__ gsc)
{
  __shared__ float Xitem[48];
  __shared__ int icode[16];
  __shared__ __align__(16) float4 xsh[256][5];   // slot 4 = pad -> 20-word stride
  const int b = blockIdx.y, tid = threadIdx.x;

  const int l = blockIdx.x * 256 + tid;
  const size_t off = (size_t)b * LLx + l;
  const int gid = lg[off];

  if (tid < 48) {
    const int seg = tid >> 4, e = tid & 15;
    const int id = (seg == 0) ? ig[b] : (seg == 1) ? ish[b] : ici[b];
    Xitem[tid] = emb[(size_t)id * 16 + e];
  }
  __syncthreads();
  if (tid < 16) {
    float dd = 0.f;
    for (int e = 0; e < 48; ++e) dd += Xitem[e] * Hm[e * 16 + tid];
    icode[tid] = (dd > 0.f) ? 1 : (dd < 0.f ? -1 : 0);
  }

  const int srow = tid >> 2;
  const int q = tid & 3;
  const size_t bbase = (size_t)b * LLx + (size_t)blockIdx.x * 256;

  float d[16];
  #pragma unroll
  for (int m = 0; m < 16; ++m) d[m] = 0.f;

  #pragma unroll
  for (int seg = 0; seg < 3; ++seg) {
    const int* idarr = (seg == 0) ? lg : (seg == 1) ? lsh : lc;
    #pragma unroll
    for (int jj = 0; jj < 4; ++jj) {
      const int pos = jj * 64 + srow;
      const int id = idarr[bbase + pos];
      xsh[pos][q] = *(const float4*)(emb + (size_t)id * 16 + q * 4);
    }
    __syncthreads();
    if (gid != 0) {
      float x[16];
      #pragma unroll
      for (int qq = 0; qq < 4; ++qq) {
        const float4 r = xsh[tid][qq];
        x[qq * 4 + 0] = r.x; x[qq * 4 + 1] = r.y;
        x[qq * 4 + 2] = r.z; x[qq * 4 + 3] = r.w;
      }
      const float* hb = Hm + seg * 256;
      #pragma unroll
      for (int i = 0; i < 16; ++i) {
        const float xi = x[i];
        #pragma unroll
        for (int mc = 0; mc < 4; ++mc) {
          const float4 h4 = *(const float4*)(hb + i * 16 + mc * 4);
          d[mc * 4 + 0] += xi * h4.x;
          d[mc * 4 + 1] += xi * h4.y;
          d[mc * 4 + 2] += xi * h4.z;
          d[mc * 4 + 3] += xi * h4.w;
        }
      }
    }
    if (seg < 2) __syncthreads();
  }

  int sc = -1;
  if (gid != 0) {
    sc = 0;
    #pragma unroll
    for (int m = 0; m < 16; ++m) {
      const int cs = (d[m] > 0.f) ? 1 : (d[m] < 0.f ? -1 : 0);
      sc += (cs == icode[m]) ? 1 : 0;
    }
  }
  gsc[off] = (signed char)sc;
}

// ---------------------------------------------------------------------------
// Kernel 2: fused tail — topk + {short-MHA || long-MHA} + MLP.
// R8 changes vs R7 (structure otherwise verbatim):
//  * V buffers TRANSPOSED: vhs_sT[48][65], vhs_lT[48][49]. Writes are
//    (fixed row j, consecutive cols t) -> conflict-free; PV reads (fixed k,
//    48 rows, stride 65/49 both odd mod 32) -> <=2-way. Kills the measured
//    4.7M conflicts from the old vhs[t][j] 32-way writes.
//  * Short V chunked 2x64: threads t<64 store V in P5; threads 64-127 HOLD
//    vh[48] in regs through softmax and store between PV pass 0 and pass 1.
//    PV accumulates k=0..63 then 64..127 -> identical summation order ->
//    bit-identical. LDS 43.5KB -> ~30.5KB -> 4+ blocks/CU.
//  * __launch_bounds__(256,2): 128-VGPR headroom (R6-proven; R4/R5 showed
//    the spill failure modes). Spill tripwire = WRITE_SIZE of this dispatch.
// ---------------------------------------------------------------------------
__device__ __forceinline__ float block_sum256(float v, float* red) {
  #pragma unroll
  for (int m = 32; m >= 1; m >>= 1) v += __shfl_xor(v, m, 64);
  const int lane = threadIdx.x & 63, wave = threadIdx.x >> 6;
  if (lane == 0) red[wave] = v;
  __syncthreads();
  const float t = red[0] + red[1] + red[2] + red[3];
  __syncthreads();
  return t;
}

__global__ __launch_bounds__(256, 2) void k_fused(
    const int* __restrict__ sg, const int* __restrict__ ss, const int* __restrict__ scd,
    const int* __restrict__ lg, const int* __restrict__ ls, const int* __restrict__ lcd,
    const int* __restrict__ ig, const int* __restrict__ ish, const int* __restrict__ ici,
    const int* __restrict__ uid, const int* __restrict__ u1, const int* __restrict__ u2,
    const int* __restrict__ u3, const int* __restrict__ u4,
    const float* __restrict__ emb,
    const float* __restrict__ sWq, const float* __restrict__ sbq,
    const float* __restrict__ sWk, const float* __restrict__ sbk,
    const float* __restrict__ sWv, const float* __restrict__ sbv,
    const float* __restrict__ sWo, const float* __restrict__ sbo,
    const float* __restrict__ lWq, const float* __restrict__ lbq,
    const float* __restrict__ lWk, const float* __restrict__ lbk,
    const float* __restrict__ lWv, const float* __restrict__ lbv,
    const float* __restrict__ lWo, const float* __restrict__ lbo,
    const signed char* __restrict__ gsc,
    const float* __restrict__ W1, const float* __restrict__ b1,
    const float* __restrict__ g1, const float* __restrict__ be1,
    const float* __restrict__ W2, const float* __restrict__ b2,
    const float* __restrict__ g2, const float* __restrict__ be2,
    const float* __restrict__ W3, const float* __restrict__ b3,
    float* __restrict__ out)
{
  __shared__ float Xitem[48];
  __shared__ float qh_s[48], qh_l[48];
  __shared__ float vhs_sT[48][65];     // transposed, half of K (64 cols + pad)
  __shared__ float scs_s[8][LSx + 4];
  __shared__ float vhs_lT[48][TOPKx + 1];
  __shared__ float scs_l[8][TOPKx + 4];
  __shared__ float osm_s[48], osm_l[48];
  __shared__ unsigned char validf_s[LSx];
  __shared__ unsigned char validf_l[TOPKx];
  __shared__ int hist[18], wsum[4], nv[4], selsh[TOPKx];
  __shared__ int cnt_above;
  __shared__ __align__(16) float x[224];
  __shared__ __align__(16) float h1[200];
  __shared__ float h2[80];
  __shared__ float red[4];

  const int b = blockIdx.x, tid = threadIdx.x;
  const bool shorth = tid < 128;
  const int t = shorth ? tid : tid - 128;

  // each thread owns 8 contiguous scores, in registers (verbatim k_topk)
  const int2 myv = ((const int2*)(gsc + (size_t)b * LLx))[tid];
  signed char loc[8];
  *(int2*)loc = myv;

  // ---- P0: item embed + user embed + topk init ----
  if (tid < 48) {
    const int seg = tid >> 4, e = tid & 15;
    const int id = (seg == 0) ? ig[b] : (seg == 1) ? ish[b] : ici[b];
    Xitem[tid] = emb[(size_t)id * 16 + e];
  }
  if (tid >= 160 && tid < 240) {
    const int u = tid - 160;
    const int f = u >> 4;
    const int id = (f == 0) ? uid[b] : (f == 1) ? u1[b] : (f == 2) ? u2[b]
                 : (f == 3) ? u3[b] : u4[b];
    x[48 + u] = emb[(size_t)id * 16 + (u & 15)];   // (48+u)&15 == u&15
  }
  if (tid < 18) hist[tid] = 0;
  if (tid == 0) cnt_above = 0;
  __syncthreads();

  // ---- P1: histogram atomics + both q projections + x[0:48] copy ----
  #pragma unroll
  for (int j = 0; j < 8; ++j) atomicAdd(&hist[(int)loc[j] + 1], 1);
  if (tid < 48) {
    float a = sbq[tid];
    for (int e = 0; e < 48; ++e) a += Xitem[e] * sWq[e * 48 + tid];
    qh_s[tid] = a;
  } else if (tid >= 64 && tid < 112) {
    x[tid - 64] = Xitem[tid - 64];
  } else if (tid >= 128 && tid < 176) {
    float a = lbq[t];
    for (int e = 0; e < 48; ++e) a += Xitem[e] * lWq[e * 48 + t];
    qh_l[t] = a;
  }
  __syncthreads();

  // ---- P2: threshold + tie-rank scan (verbatim k_topk) ----
  int above = 0, tval = -1, need = 0;
  for (int s = 16; s >= -1; --s) {
    const int c = hist[s + 1];
    if (above + c >= TOPKx) { tval = s; need = TOPKx - above; break; }
    above += c;
  }
  const int base_l = tid * (LLx / 256);
  int cnt = 0;
  #pragma unroll
  for (int j = 0; j < 8; ++j) cnt += ((int)loc[j] == tval) ? 1 : 0;
  int v = cnt;
  const int lane = tid & 63, wave = tid >> 6;
  #pragma unroll
  for (int o = 1; o < 64; o <<= 1) {
    const int u = __shfl_up(v, o, 64);
    if (lane >= o) v += u;
  }
  if (lane == 63) wsum[wave] = v;
  __syncthreads();
  int rank = v - cnt;
  for (int w = 0; w < wave; ++w) rank += wsum[w];

  #pragma unroll
  for (int j = 0; j < 8; ++j) {
    const int l = base_l + j;
    const int s = (int)loc[j];
    if (s > tval) {
      const int slot = atomicAdd(&cnt_above, 1);
      selsh[slot] = l;
    } else if (s == tval) {
      if (rank < need) selsh[above + rank] = l;
      ++rank;
    }
  }
  __syncthreads();   // selsh ready

  // ---- P4: key id loads + per-half valid counts ----
  int gid = 0, sid = 0, cid = 0;
  if (shorth) {
    const size_t off = (size_t)b * LSx + t;
    gid = sg[off]; sid = ss[off]; cid = scd[off];
  } else if (t < TOPKx) {
    const int pos = selsh[t];
    const size_t off = (size_t)b * LLx + pos;
    gid = lg[off]; sid = ls[off]; cid = lcd[off];
  }
  const unsigned long long bal = __ballot(gid != 0);
  if ((tid & 63) == 0) nv[tid >> 6] = __popcll(bal);
  __syncthreads();
  const int nval = shorth ? (nv[0] + nv[1]) : (nv[2] + nv[3]);

  // ---- P5: K/V projections (verbatim chains, transposed V stores) ----
  float vh[48];                       // threads 64..127 hold this into P7b
  if (shorth) {
    validf_s[t] = (unsigned char)(t < nval);   // short: mask = position < slen
    float kh[48];
    #pragma unroll
    for (int j = 0; j < 48; ++j) { kh[j] = sbk[j]; vh[j] = sbv[j]; }
    const int ids3[3] = {gid, sid, cid};
    #pragma unroll
    for (int seg = 0; seg < 3; ++seg) {
      const float* row = emb + (size_t)ids3[seg] * 16;
      #pragma unroll
      for (int i4 = 0; i4 < 4; ++i4) {
        const float4 xv = ((const float4*)row)[i4];
        const float xs[4] = {xv.x, xv.y, xv.z, xv.w};
        #pragma unroll
        for (int c = 0; c < 4; ++c) {
          const int e = seg * 16 + i4 * 4 + c;
          const float* wkr = sWk + e * 48;
          const float* wvr = sWv + e * 48;
          const float xe = xs[c];
          #pragma unroll
          for (int j = 0; j < 48; ++j) {
            kh[j] += xe * wkr[j];
            vh[j] += xe * wvr[j];
          }
        }
      }
    }
    #pragma unroll
    for (int h = 0; h < 8; ++h) {
      float s = 0.f;
      #pragma unroll
      for (int d = 0; d < 6; ++d) s += qh_s[h * 6 + d] * kh[h * 6 + d];
      scs_s[h][t] = s * 0.40824829046386301637f;   // 1/sqrt(6)
    }
    if (t < 64) {                      // chunk 0 stores now; t>=64 holds vh
      #pragma unroll
      for (int j = 0; j < 48; ++j) vhs_sT[j][t] = vh[j];
    }
  } else if (t < TOPKx) {
    validf_l[t] = (unsigned char)(gid != 0);   // long: mask = gid != 0
    float kh[48];
    #pragma unroll
    for (int j = 0; j < 48; ++j) { kh[j] = lbk[j]; vh[j] = lbv[j]; }
    const int ids3[3] = {gid, sid, cid};
    #pragma unroll
    for (int seg = 0; seg < 3; ++seg) {
      const float* row = emb + (size_t)ids3[seg] * 16;
      #pragma unroll
      for (int i4 = 0; i4 < 4; ++i4) {
        const float4 xv = ((const float4*)row)[i4];
        const float xs[4] = {xv.x, xv.y, xv.z, xv.w};
        #pragma unroll
        for (int c = 0; c < 4; ++c) {
          const int e = seg * 16 + i4 * 4 + c;
          const float* wkr = lWk + e * 48;
          const float* wvr = lWv + e * 48;
          const float xe = xs[c];
          #pragma unroll
          for (int j = 0; j < 48; ++j) {
            kh[j] += xe * wkr[j];
            vh[j] += xe * wvr[j];
          }
        }
      }
    }
    #pragma unroll
    for (int h = 0; h < 8; ++h) {
      float s = 0.f;
      #pragma unroll
      for (int d = 0; d < 6; ++d) s += qh_l[h * 6 + d] * kh[h * 6 + d];
      scs_l[h][t] = s * 0.40824829046386301637f;
    }
    #pragma unroll
    for (int j = 0; j < 48; ++j) vhs_lT[j][t] = vh[j];
  }
  __syncthreads();

  // ---- P6: softmax (each half: 8 head-groups of 16 lanes, verbatim) ----
  {
    const int h = t >> 4, l16 = t & 15;
    if (shorth) {
      float amax = -INFINITY;
      for (int k = l16; k < LSx; k += 16) if (validf_s[k]) amax = fmaxf(amax, scs_s[h][k]);
      #pragma unroll
      for (int m = 1; m < 16; m <<= 1) amax = fmaxf(amax, __shfl_xor(amax, m, 16));
      if (nval == 0) {
        for (int k = l16; k < LSx; k += 16) scs_s[h][k] = 1.0f / (float)LSx;
      } else {
        float ssum = 0.f;
        for (int k = l16; k < LSx; k += 16) {
          const float ev = validf_s[k] ? expf(scs_s[h][k] - amax) : 0.f;
          scs_s[h][k] = ev;
          ssum += ev;
        }
        #pragma unroll
        for (int m = 1; m < 16; m <<= 1) ssum += __shfl_xor(ssum, m, 16);
        const float inv = 1.0f / ssum;
        for (int k = l16; k < LSx; k += 16) scs_s[h][k] *= inv;
      }
    } else {
      float amax = -INFINITY;
      for (int k = l16; k < TOPKx; k += 16) if (validf_l[k]) amax = fmaxf(amax, scs_l[h][k]);
      #pragma unroll
      for (int m = 1; m < 16; m <<= 1) amax = fmaxf(amax, __shfl_xor(amax, m, 16));
      if (nval == 0) {
        for (int k = l16; k < TOPKx; k += 16) scs_l[h][k] = 1.0f / (float)TOPKx;
      } else {
        float ssum = 0.f;
        for (int k = l16; k < TOPKx; k += 16) {
          const float ev = validf_l[k] ? expf(scs_l[h][k] - amax) : 0.f;
          scs_l[h][k] = ev;
          ssum += ev;
        }
        #pragma unroll
        for (int m = 1; m < 16; m <<= 1) ssum += __shfl_xor(ssum, m, 16);
        const float inv = 1.0f / ssum;
        for (int k = l16; k < TOPKx; k += 16) scs_l[h][k] *= inv;
      }
    }
  }
  __syncthreads();

  // ---- P7a: PV pass 0 (short k=0..63) + full long PV ----
  float acc = 0.f;
  int hh = 0;
  if (tid < 48) {
    hh = tid / 6;
    for (int k = 0; k < 64; ++k) acc += scs_s[hh][k] * vhs_sT[tid][k];
  } else if (!shorth && t < 48) {
    const int h = t / 6;
    float a = 0.f;
    for (int k = 0; k < TOPKx; ++k) a += scs_l[h][k] * vhs_lT[t][k];
    osm_l[t] = a;
  }
  __syncthreads();

  // ---- P7b: chunk-1 V store (threads 64..127 release held vh) ----
  if (shorth && t >= 64) {
    #pragma unroll
    for (int j = 0; j < 48; ++j) vhs_sT[j][t - 64] = vh[j];
  }
  __syncthreads();

  // ---- P7c: PV pass 1 (short k=64..127; same accumulator, same order) ----
  if (tid < 48) {
    for (int k = 64; k < LSx; ++k) acc += scs_s[hh][k] * vhs_sT[tid][k - 64];
    osm_s[tid] = acc;
  }
  __syncthreads();

  // ---- P8: output projections into MLP input x (verbatim chains) ----
  if (tid < 48) {
    float r = sbo[tid];
    for (int j = 0; j < 48; ++j) r += osm_s[j] * sWo[j * 48 + tid];
    x[128 + tid] = r;
  } else if (!shorth && t < 48) {
    float r = lbo[t];
    for (int j = 0; j < 48; ++j) r += osm_l[j] * lWo[j * 48 + t];
    x[176 + t] = r;
  }
  __syncthreads();

  // ---- P9: MLP head (verbatim k_mlp body) ----
  float v1 = 0.f;
  if (tid < 200) {
    v1 = b1[tid];
    for (int i4 = 0; i4 < 56; ++i4) {
      const float4 xv = *(const float4*)(x + i4 * 4);
      const float* w = W1 + i4 * 4 * 200 + tid;
      v1 += xv.x * w[0];
      v1 += xv.y * w[200];
      v1 += xv.z * w[400];
      v1 += xv.w * w[600];
    }
  }
  const float mean1 = block_sum256((tid < 200) ? v1 : 0.f, red) * (1.0f / 200.0f);
  const float dv = (tid < 200) ? (v1 - mean1) : 0.f;
  const float var1 = block_sum256(dv * dv, red) * (1.0f / 200.0f);
  if (tid < 200) {
    const float y = (v1 - mean1) * rsqrtf(var1 + 1e-3f) * g1[tid] + be1[tid];
    h1[tid] = fmaxf(y, 0.f);
  }
  __syncthreads();

  float v2 = 0.f;
  if (tid < 80) {
    v2 = b2[tid];
    for (int i4 = 0; i4 < 50; ++i4) {
      const float4 xv = *(const float4*)(h1 + i4 * 4);
      const float* w = W2 + i4 * 4 * 80 + tid;
      v2 += xv.x * w[0];
      v2 += xv.y * w[80];
      v2 += xv.z * w[160];
      v2 += xv.w * w[240];
    }
  }
  const float mean2 = block_sum256((tid < 80) ? v2 : 0.f, red) * (1.0f / 80.0f);
  const float dv2 = (tid < 80) ? (v2 - mean2) : 0.f;
  const float var2 = block_sum256(dv2 * dv2, red) * (1.0f / 80.0f);
  if (tid < 80) {
    const float y = (v2 - mean2) * rsqrtf(var2 + 1e-3f) * g2[tid] + be2[tid];
    h2[tid] = fmaxf(y, 0.f);
  }
  __syncthreads();

  const float p = (tid < 80) ? h2[tid] * W3[tid] : 0.f;
  const float z = block_sum256(p, red);
  if (tid == 0) {
    out[b] = 1.0f / (1.0f + expf(-(z + b3[0])));
  }
}

// ---------------------------------------------------------------------------
extern "C" void kernel_launch(void* const* d_in, const int* in_sizes, int n_in,
                              void* d_out, int out_size, void* d_ws, size_t ws_size,
                              hipStream_t stream) {
  (void)in_sizes; (void)n_in; (void)out_size; (void)ws_size;
  const int* uid = (const int*)d_in[0];
  const int* u1  = (const int*)d_in[1];
  const int* u2  = (const int*)d_in[2];
  const int* u3  = (const int*)d_in[3];
  const int* u4  = (const int*)d_in[4];
  const int* ig  = (const int*)d_in[5];
  const int* ish = (const int*)d_in[6];
  const int* ici = (const int*)d_in[7];
  const int* sg  = (const int*)d_in[8];
  const int* ss  = (const int*)d_in[9];
  const int* scd = (const int*)d_in[10];
  const int* lg  = (const int*)d_in[11];
  const int* ls  = (const int*)d_in[12];
  const int* lcd = (const int*)d_in[13];
  const float* emb = (const float*)d_in[14];
  const float* Hm  = (const float*)d_in[15];
  const float* sWq = (const float*)d_in[16];
  const float* sbq = (const float*)d_in[17];
  const float* sWk = (const float*)d_in[18];
  const float* sbk = (const float*)d_in[19];
  const float* sWv = (const float*)d_in[20];
  const float* sbv = (const float*)d_in[21];
  const float* sWo = (const float*)d_in[22];
  const float* sbo = (const float*)d_in[23];
  const float* lWq = (const float*)d_in[24];
  const float* lbq = (const float*)d_in[25];
  const float* lWk = (const float*)d_in[26];
  const float* lbk = (const float*)d_in[27];
  const float* lWv = (const float*)d_in[28];
  const float* lbv = (const float*)d_in[29];
  const float* lWo = (const float*)d_in[30];
  const float* lbo = (const float*)d_in[31];
  const float* W1 = (const float*)d_in[32];
  const float* b1 = (const float*)d_in[33];
  const float* g1 = (const float*)d_in[34];
  const float* be1 = (const float*)d_in[35];
  const float* W2 = (const float*)d_in[36];
  const float* b2 = (const float*)d_in[37];
  const float* g2 = (const float*)d_in[38];
  const float* be2 = (const float*)d_in[39];
  const float* W3 = (const float*)d_in[40];
  const float* b3 = (const float*)d_in[41];
  float* out = (float*)d_out;

  // workspace: [gsc i8: BB*LLx = 2MB]
  signed char* gsc = (signed char*)d_ws;

  k_score<<<dim3(LLx / 256, BB), dim3(256), 0, stream>>>(
      lg, ls, lcd, ig, ish, ici, emb, Hm, gsc);
  k_fused<<<dim3(BB), dim3(256), 0, stream>>>(
      sg, ss, scd, lg, ls, lcd, ig, ish, ici,
      uid, u1, u2, u3, u4, emb,
      sWq, sbq, sWk, sbk, sWv, sbv, sWo, sbo,
      lWq, lbq, lWk, lbk, lWv, lbv, lWo, lbo,
      gsc,
      W1, b1, g1, be1, W2, b2, g2, be2, W3, b3, out);
}